// Round 3
// baseline (268.603 us; speedup 1.0000x reference)
//
#include <hip/hip_runtime.h>
#include <math.h>

#define NPTS 300000
#define K 64
#define P 32
#define DETC 1e-16f
// one accumulator copy: [0,64) N_k | [64,128) S_k | [128,2176) M[d][k]
#define WS_FLOATS (K + K + K * P)
// striped copies to avoid same-line atomic serialization across 8 XCDs
#define NCOPIES 32

#define NBLOCKS 1024
#define NTHREADS 256
#define NWAVES (NBLOCKS * (NTHREADS / 64))            // 4096
#define CHUNK ((NPTS + NWAVES - 1) / NWAVES)          // 74

// ---- DPP helpers: sum across 64 lanes with VALU-only latency ----
#define DPP_ADD(v, ctrl)                                                     \
    v += __int_as_float(__builtin_amdgcn_update_dpp(                         \
        0, __float_as_int(v), (ctrl), 0xF, 0xF, true))

__device__ __forceinline__ float rl(float x, int lane) {
    return __int_as_float(__builtin_amdgcn_readlane(__float_as_int(x), lane));
}

__global__ __launch_bounds__(NTHREADS, 2) void em_pass(
    const float* __restrict__ mu_phi,
    const float* __restrict__ log_cov_phi,
    const float* __restrict__ pi_k,
    const float* __restrict__ mu_k,
    const float* __restrict__ log_cov_k,
    float* __restrict__ gamma_out,
    float* __restrict__ out_tail,   // pi_new | mu_new | log_cov_new
    float* __restrict__ ws)
{
    const int lane = threadIdx.x & 63;                 // = cluster index
    const int wave = threadIdx.x >> 6;
    const int gw = __builtin_amdgcn_readfirstlane(blockIdx.x * (NTHREADS / 64) + wave);

    // asm-opaque VGPR zero: defeats uniformity analysis so per-point row
    // loads become VECTOR broadcast loads (vmcnt-counted, in-order,
    // pipelineable) instead of s_load + lgkmcnt(0) full drains.
    int vzero;
    asm volatile("v_mov_b32 %0, 0" : "=v"(vzero));

    // ---- per-lane cluster constants (icov folded into mk2) ----
    const float lck  = log_cov_k[lane];
    const float icov = __expf(-lck);
    const float pik  = pi_k[lane];

    float mk2[P];
    float n2k = 0.f;
#pragma unroll
    for (int d = 0; d < P; ++d) {
        const float m = mu_k[lane * P + d];
        mk2[d] = icov * m;
        n2k = fmaf(m, m, n2k);
    }
    // exponent = sum_d row[d]*mk2[d] - 0.5*icov*u + 16*lcp - Ak
    const float Ak     = 0.5f * (32.f * lck - 32.f + icov * n2k) - __logf(pik);
    const float negAk  = -Ak;
    const float nhicov = -0.5f * icov;

    float accN = 0.f, accS = 0.f;
    float accM[P];
#pragma unroll
    for (int d = 0; d < P; ++d) accM[d] = 0.f;

    const int start = gw * CHUNK;
    const int end0  = (start + CHUNK < NPTS) ? (start + CHUNK) : NPTS;

    for (int gb = start; gb < end0; gb += 64) {
        const int cnt = (end0 - gb < 64) ? (end0 - gb) : 64;

        // ---- u-phase: lane = point. coalesced-ish float4 loads, warms L2/L1 ----
        float u_v = 0.f, bl_v = 0.f;
        if (lane < cnt) {
            const float4* r4 =
                reinterpret_cast<const float4*>(mu_phi + (size_t)(gb + lane) * P);
            float n2 = 0.f;
#pragma unroll 1
            for (int q = 0; q < 8; q += 4) {
                float4 a = r4[q], b = r4[q + 1], c = r4[q + 2], e = r4[q + 3];
                n2 = fmaf(a.x, a.x, n2); n2 = fmaf(a.y, a.y, n2);
                n2 = fmaf(a.z, a.z, n2); n2 = fmaf(a.w, a.w, n2);
                n2 = fmaf(b.x, b.x, n2); n2 = fmaf(b.y, b.y, n2);
                n2 = fmaf(b.z, b.z, n2); n2 = fmaf(b.w, b.w, n2);
                n2 = fmaf(c.x, c.x, n2); n2 = fmaf(c.y, c.y, n2);
                n2 = fmaf(c.z, c.z, n2); n2 = fmaf(c.w, c.w, n2);
                n2 = fmaf(e.x, e.x, n2); n2 = fmaf(e.y, e.y, n2);
                n2 = fmaf(e.z, e.z, n2); n2 = fmaf(e.w, e.w, n2);
            }
            const float lcp = log_cov_phi[gb + lane];
            u_v  = fmaf(32.f, __expf(lcp), n2);   // P*e^lcp + ||phi||^2
            bl_v = 16.f * lcp;
        }

        // ---- per-point phase: lane = cluster; row via VECTOR broadcast loads ----
#pragma unroll 2
        for (int p = 0; p < cnt; ++p) {
            const int i = gb + p;
            const float u_s  = rl(u_v, p);
            const float bl_s = rl(bl_v, p);
            // vzero makes the address per-lane (all equal) -> global_load_dwordx4
            // broadcast of one 128B line; in-order vmcnt lets loads pipeline
            // across iterations.
            const float* row = mu_phi + (size_t)i * P + vzero;

            float4 r0 = reinterpret_cast<const float4*>(row)[0];
            float4 r1 = reinterpret_cast<const float4*>(row)[1];
            float4 r2 = reinterpret_cast<const float4*>(row)[2];
            float4 r3 = reinterpret_cast<const float4*>(row)[3];
            float4 r4 = reinterpret_cast<const float4*>(row)[4];
            float4 r5 = reinterpret_cast<const float4*>(row)[5];
            float4 r6 = reinterpret_cast<const float4*>(row)[6];
            float4 r7 = reinterpret_cast<const float4*>(row)[7];

            // 4 independent FMA chains (8 deep each)
            float d0 = 0.f, d1 = 0.f, d2 = 0.f, d3 = 0.f;
#define DOT4(q, base)                                                        \
            d0 = fmaf(q.x, mk2[base + 0], d0);                               \
            d1 = fmaf(q.y, mk2[base + 1], d1);                               \
            d2 = fmaf(q.z, mk2[base + 2], d2);                               \
            d3 = fmaf(q.w, mk2[base + 3], d3)
            DOT4(r0, 0); DOT4(r1, 4); DOT4(r2, 8); DOT4(r3, 12);
            DOT4(r4, 16); DOT4(r5, 20); DOT4(r6, 24); DOT4(r7, 28);
#undef DOT4
            const float dot = (d0 + d1) + (d2 + d3);

            // arg = dot + (nhicov*u - Ak) + 16*lcp
            const float tpart = fmaf(nhicov, u_s, negAk);
            const float w = __expf((dot + tpart) + bl_s);

            // wave-64 sum via DPP (VALU) + readlane combine
            float v = w;
            DPP_ADD(v, 0xB1);   // quad_perm xor1
            DPP_ADD(v, 0x4E);   // quad_perm xor2
            DPP_ADD(v, 0x128);  // row_ror:8
            DPP_ADD(v, 0x124);  // row_ror:4  -> each lane = its 16-row sum
            const float sum = (rl(v, 0) + rl(v, 16)) + (rl(v, 32) + rl(v, 48));

            const float g = fmaf(w, __builtin_amdgcn_rcpf(sum), DETC);
            __builtin_nontemporal_store(g, gamma_out + (size_t)i * K + lane); // coalesced 256B

            accN += g;
            accS  = fmaf(g, u_s, accS);
#define ACC4(q, base)                                                        \
            accM[base + 0] = fmaf(g, q.x, accM[base + 0]);                   \
            accM[base + 1] = fmaf(g, q.y, accM[base + 1]);                   \
            accM[base + 2] = fmaf(g, q.z, accM[base + 2]);                   \
            accM[base + 3] = fmaf(g, q.w, accM[base + 3])
            ACC4(r0, 0); ACC4(r1, 4); ACC4(r2, 8); ACC4(r3, 12);
            ACC4(r4, 16); ACC4(r5, 20); ACC4(r6, 24); ACC4(r7, 28);
#undef ACC4
        }
    }

    // ---- block combine in LDS, then one set of striped global atomics ----
    __shared__ float red[WS_FLOATS];   // [0,K) N | [K,2K) S | [2K,..) M[d][k]
    for (int idx = threadIdx.x; idx < WS_FLOATS; idx += NTHREADS) red[idx] = 0.f;
    __syncthreads();

    atomicAdd(&red[lane], accN);
    atomicAdd(&red[K + lane], accS);
#pragma unroll
    for (int d = 0; d < P; ++d) atomicAdd(&red[2 * K + d * K + lane], accM[d]);
    __syncthreads();

    // striped cross-block combine: contention per address = NBLOCKS/NCOPIES
    float* wsc = ws + (size_t)(blockIdx.x & (NCOPIES - 1)) * WS_FLOATS;
    for (int idx = threadIdx.x; idx < WS_FLOATS; idx += NTHREADS)
        atomicAdd(&wsc[idx], red[idx]);
    __syncthreads();   // all this block's global atomics drained

    // ---- decoupled finalize: last block reduces the copies + small outputs ----
    __shared__ int lastf;
    if (threadIdx.x == 0) {
        __threadfence();
        const int c = atomicAdd((int*)(ws + (size_t)NCOPIES * WS_FLOATS), 1);
        lastf = (c == NBLOCKS - 1);
    }
    __syncthreads();
    if (lastf) {
        __threadfence();
        for (int idx = threadIdx.x; idx < WS_FLOATS; idx += NTHREADS) {
            float s = 0.f;
#pragma unroll 4
            for (int c = 0; c < NCOPIES; ++c)
                s += __hip_atomic_load(&ws[(size_t)c * WS_FLOATS + idx],
                                       __ATOMIC_RELAXED, __HIP_MEMORY_SCOPE_AGENT);
            red[idx] = s;
        }
        __syncthreads();

        const int k = threadIdx.x;
        if (k < K) {
            const float Nk = red[k];
            const float S  = red[K + k];
            float* pi_new      = out_tail;
            float* mu_new      = out_tail + K;
            float* log_cov_new = out_tail + K + K * P;

            pi_new[k] = Nk / (float)NPTS;
            const float invN = 1.f / Nk;
            float m2 = 0.f;
#pragma unroll
            for (int d = 0; d < P; ++d) {
                const float md = red[2 * K + d * K + k] * invN;
                mu_new[k * P + d] = md;
                m2 = fmaf(md, md, m2);
            }
            const float cov = (S - Nk * m2) / (32.f * Nk);
            log_cov_new[k] = logf(cov);
        }
    }
}

extern "C" void kernel_launch(void* const* d_in, const int* in_sizes, int n_in,
                              void* d_out, int out_size, void* d_ws, size_t ws_size,
                              hipStream_t stream)
{
    const float* mu_phi      = (const float*)d_in[0];
    const float* log_cov_phi = (const float*)d_in[1];
    const float* pi_k        = (const float*)d_in[2];
    const float* mu_k        = (const float*)d_in[3];
    const float* log_cov_k   = (const float*)d_in[4];
    float* out = (float*)d_out;
    float* ws  = (float*)d_ws;

    hipMemsetAsync(ws, 0, ((size_t)NCOPIES * WS_FLOATS + 1) * sizeof(float), stream);
    em_pass<<<NBLOCKS, NTHREADS, 0, stream>>>(mu_phi, log_cov_phi, pi_k, mu_k,
                                              log_cov_k, out,
                                              out + (size_t)NPTS * K, ws);
}

// Round 4
// 248.074 us; speedup vs baseline: 1.0828x; 1.0828x over previous
//
#include <hip/hip_runtime.h>
#include <math.h>

#define NPTS 300000
#define K 64
#define P 32
#define DETC 1e-16f
// one accumulator copy: [0,64) N_k | [64,128) S_k | [128,2176) M[d][k]
#define WS_FLOATS (K + K + K * P)
// striped copies to avoid same-line atomic serialization across 8 XCDs
#define NCOPIES 32

#define NTHREADS 256
#define WPB (NTHREADS / 64)                    // 4 waves / block
#define TILE 64                                // points per wave
#define NTILES ((NPTS + TILE - 1) / TILE)      // 4688
#define NBLOCKS ((NTILES + WPB - 1) / WPB)     // 1172

// ---- DPP helpers: sum across 64 lanes with VALU-only latency ----
#define DPP_ADD(v, ctrl)                                                     \
    v += __int_as_float(__builtin_amdgcn_update_dpp(                         \
        0, __float_as_int(v), (ctrl), 0xF, 0xF, true))

__device__ __forceinline__ float rl(float x, int lane) {
    return __int_as_float(__builtin_amdgcn_readlane(__float_as_int(x), lane));
}

__global__ __launch_bounds__(NTHREADS, 4) void em_pass(
    const float* __restrict__ mu_phi,
    const float* __restrict__ log_cov_phi,
    const float* __restrict__ pi_k,
    const float* __restrict__ mu_k,
    const float* __restrict__ log_cov_k,
    float* __restrict__ gamma_out,
    float* __restrict__ out_tail,   // pi_new | mu_new | log_cov_new
    float* __restrict__ ws)
{
    const int lane = threadIdx.x & 63;                 // = cluster index
    const int wave = threadIdx.x >> 6;
    const int gw = __builtin_amdgcn_readfirstlane(blockIdx.x * WPB + wave); // tile id

    // per-wave LDS row tile, quad-transposed: stq[q][lane] (q = float4 idx)
    //  - write: lane l stores its row's quad q at stq[q][l] -> 16B-stride
    //    across lanes = fully-sequential conflict-free ds_write_b128
    //  - read : all lanes read stq[q][p] -> same-address broadcast (free)
    // red[] (block combine) overlays the staging area after the main loop.
    __shared__ float4 stq_all[WPB][8][64];             // 32 KB
    float4* stq = &stq_all[wave][0][0];
    float* red = reinterpret_cast<float*>(stq_all);    // [0,K) N |[K,2K) S |[2K,..) M

    // ---- per-lane cluster constants (icov folded into mk2) ----
    const float lck  = log_cov_k[lane];
    const float icov = __expf(-lck);
    const float pik  = pi_k[lane];

    float mk2[P];
    float n2k = 0.f;
#pragma unroll
    for (int d = 0; d < P; ++d) {
        const float m = mu_k[lane * P + d];
        mk2[d] = icov * m;
        n2k = fmaf(m, m, n2k);
    }
    // exponent = sum_d row[d]*mk2[d] - 0.5*icov*u + 16*lcp - Ak
    const float Ak     = 0.5f * (32.f * lck - 32.f + icov * n2k) - __logf(pik);
    const float negAk  = -Ak;
    const float nhicov = -0.5f * icov;

    float accN = 0.f, accS = 0.f;
    float accM[P];
#pragma unroll
    for (int d = 0; d < P; ++d) accM[d] = 0.f;

    const int start = gw * TILE;
    const int cnt   = (NPTS - start < TILE) ? (NPTS - start) : TILE;

    // ---- u-phase: lane = point. Coalesced float4 loads -> LDS stage + n2 ----
    float u_v = 0.f, bl_v = 0.f;
    if (lane < cnt) {
        const float4* r4 =
            reinterpret_cast<const float4*>(mu_phi + (size_t)(start + lane) * P);
        float n2 = 0.f;
        {
            float4 a = r4[0], b = r4[1], c = r4[2], e = r4[3];
            stq[0 * 64 + lane] = a; stq[1 * 64 + lane] = b;
            stq[2 * 64 + lane] = c; stq[3 * 64 + lane] = e;
            n2 = fmaf(a.x, a.x, n2); n2 = fmaf(a.y, a.y, n2);
            n2 = fmaf(a.z, a.z, n2); n2 = fmaf(a.w, a.w, n2);
            n2 = fmaf(b.x, b.x, n2); n2 = fmaf(b.y, b.y, n2);
            n2 = fmaf(b.z, b.z, n2); n2 = fmaf(b.w, b.w, n2);
            n2 = fmaf(c.x, c.x, n2); n2 = fmaf(c.y, c.y, n2);
            n2 = fmaf(c.z, c.z, n2); n2 = fmaf(c.w, c.w, n2);
            n2 = fmaf(e.x, e.x, n2); n2 = fmaf(e.y, e.y, n2);
            n2 = fmaf(e.z, e.z, n2); n2 = fmaf(e.w, e.w, n2);
        }
        {
            float4 a = r4[4], b = r4[5], c = r4[6], e = r4[7];
            stq[4 * 64 + lane] = a; stq[5 * 64 + lane] = b;
            stq[6 * 64 + lane] = c; stq[7 * 64 + lane] = e;
            n2 = fmaf(a.x, a.x, n2); n2 = fmaf(a.y, a.y, n2);
            n2 = fmaf(a.z, a.z, n2); n2 = fmaf(a.w, a.w, n2);
            n2 = fmaf(b.x, b.x, n2); n2 = fmaf(b.y, b.y, n2);
            n2 = fmaf(b.z, b.z, n2); n2 = fmaf(b.w, b.w, n2);
            n2 = fmaf(c.x, c.x, n2); n2 = fmaf(c.y, c.y, n2);
            n2 = fmaf(c.z, c.z, n2); n2 = fmaf(c.w, c.w, n2);
            n2 = fmaf(e.x, e.x, n2); n2 = fmaf(e.y, e.y, n2);
            n2 = fmaf(e.z, e.z, n2); n2 = fmaf(e.w, e.w, n2);
        }
        const float lcp = log_cov_phi[start + lane];
        u_v  = fmaf(32.f, __expf(lcp), n2);   // P*e^lcp + ||phi||^2
        bl_v = 16.f * lcp;
    }
    // staging is wave-private: no __syncthreads needed, compiler orders
    // ds_write -> ds_read with lgkmcnt within the wave.

    // ---- per-point phase: lane = cluster; rows via broadcast ds_read_b128 ----
#pragma unroll 2
    for (int p = 0; p < cnt; ++p) {
        const int i = start + p;
        const float u_s  = rl(u_v, p);
        const float bl_s = rl(bl_v, p);

        // 4 independent FMA chains (8 deep each)
        float d0 = 0.f, d1 = 0.f, d2 = 0.f, d3 = 0.f;
#pragma unroll
        for (int q = 0; q < 8; ++q) {
            const float4 r = stq[q * 64 + p];          // broadcast read
            d0 = fmaf(r.x, mk2[4 * q + 0], d0);
            d1 = fmaf(r.y, mk2[4 * q + 1], d1);
            d2 = fmaf(r.z, mk2[4 * q + 2], d2);
            d3 = fmaf(r.w, mk2[4 * q + 3], d3);
        }
        const float dot = (d0 + d1) + (d2 + d3);

        // arg = dot + (nhicov*u - Ak) + 16*lcp
        const float tpart = fmaf(nhicov, u_s, negAk);
        const float w = __expf((dot + tpart) + bl_s);

        // wave-64 sum via DPP (VALU) + readlane combine
        float v = w;
        DPP_ADD(v, 0xB1);   // quad_perm xor1
        DPP_ADD(v, 0x4E);   // quad_perm xor2
        DPP_ADD(v, 0x128);  // row_ror:8
        DPP_ADD(v, 0x124);  // row_ror:4  -> each lane = its 16-row sum
        const float sum = (rl(v, 0) + rl(v, 16)) + (rl(v, 32) + rl(v, 48));

        const float g = fmaf(w, __builtin_amdgcn_rcpf(sum), DETC);
        __builtin_nontemporal_store(g, gamma_out + (size_t)i * K + lane); // coalesced 256B

        accN += g;
        accS  = fmaf(g, u_s, accS);
        // re-read quads from LDS (broadcast ~free) instead of keeping 32
        // VGPRs live across the exp/reduce chain
#pragma unroll
        for (int q = 0; q < 8; ++q) {
            const float4 r = stq[q * 64 + p];
            accM[4 * q + 0] = fmaf(g, r.x, accM[4 * q + 0]);
            accM[4 * q + 1] = fmaf(g, r.y, accM[4 * q + 1]);
            accM[4 * q + 2] = fmaf(g, r.z, accM[4 * q + 2]);
            accM[4 * q + 3] = fmaf(g, r.w, accM[4 * q + 3]);
        }
    }

    // ---- block combine in LDS (red overlays staging), striped global atomics ----
    __syncthreads();   // all waves done with their staging area
    for (int idx = threadIdx.x; idx < WS_FLOATS; idx += NTHREADS) red[idx] = 0.f;
    __syncthreads();

    atomicAdd(&red[lane], accN);
    atomicAdd(&red[K + lane], accS);
#pragma unroll
    for (int d = 0; d < P; ++d) atomicAdd(&red[2 * K + d * K + lane], accM[d]);
    __syncthreads();

    // striped cross-block combine: contention per address = NBLOCKS/NCOPIES
    float* wsc = ws + (size_t)(blockIdx.x & (NCOPIES - 1)) * WS_FLOATS;
    for (int idx = threadIdx.x; idx < WS_FLOATS; idx += NTHREADS)
        atomicAdd(&wsc[idx], red[idx]);
    __syncthreads();   // all this block's global atomics drained

    // ---- decoupled finalize: last block reduces the copies + small outputs ----
    __shared__ int lastf;
    if (threadIdx.x == 0) {
        __threadfence();
        const int c = atomicAdd((int*)(ws + (size_t)NCOPIES * WS_FLOATS), 1);
        lastf = (c == NBLOCKS - 1);
    }
    __syncthreads();
    if (lastf) {
        __threadfence();
        for (int idx = threadIdx.x; idx < WS_FLOATS; idx += NTHREADS) {
            float s = 0.f;
#pragma unroll 4
            for (int c = 0; c < NCOPIES; ++c)
                s += __hip_atomic_load(&ws[(size_t)c * WS_FLOATS + idx],
                                       __ATOMIC_RELAXED, __HIP_MEMORY_SCOPE_AGENT);
            red[idx] = s;
        }
        __syncthreads();

        const int k = threadIdx.x;
        if (k < K) {
            const float Nk = red[k];
            const float S  = red[K + k];
            float* pi_new      = out_tail;
            float* mu_new      = out_tail + K;
            float* log_cov_new = out_tail + K + K * P;

            pi_new[k] = Nk / (float)NPTS;
            const float invN = 1.f / Nk;
            float m2 = 0.f;
#pragma unroll
            for (int d = 0; d < P; ++d) {
                const float md = red[2 * K + d * K + k] * invN;
                mu_new[k * P + d] = md;
                m2 = fmaf(md, md, m2);
            }
            const float cov = (S - Nk * m2) / (32.f * Nk);
            log_cov_new[k] = logf(cov);
        }
    }
}

extern "C" void kernel_launch(void* const* d_in, const int* in_sizes, int n_in,
                              void* d_out, int out_size, void* d_ws, size_t ws_size,
                              hipStream_t stream)
{
    const float* mu_phi      = (const float*)d_in[0];
    const float* log_cov_phi = (const float*)d_in[1];
    const float* pi_k        = (const float*)d_in[2];
    const float* mu_k        = (const float*)d_in[3];
    const float* log_cov_k   = (const float*)d_in[4];
    float* out = (float*)d_out;
    float* ws  = (float*)d_ws;

    hipMemsetAsync(ws, 0, ((size_t)NCOPIES * WS_FLOATS + 1) * sizeof(float), stream);
    em_pass<<<NBLOCKS, NTHREADS, 0, stream>>>(mu_phi, log_cov_phi, pi_k, mu_k,
                                              log_cov_k, out,
                                              out + (size_t)NPTS * K, ws);
}

// Round 5
// 220.133 us; speedup vs baseline: 1.2202x; 1.1269x over previous
//
#include <hip/hip_runtime.h>
#include <math.h>

#define NPTS 300000
#define K 64
#define P 32
#define DETC 1e-16f
// one accumulator copy: [0,64) N_k | [64,128) S_k | [128,2176) M[d][k]
#define WS_FLOATS (K + K + K * P)
// striped copies to avoid same-line atomic serialization across 8 XCDs
#define NCOPIES 32

#define NTHREADS 256
#define WPB (NTHREADS / 64)                    // 4 waves / block
#define TILE 64                                // points per wave
#define NTILES ((NPTS + TILE - 1) / TILE)      // 4688
#define NBLOCKS ((NTILES + WPB - 1) / WPB)     // 1172

// ---- DPP helpers: sum across 64 lanes with VALU-only latency ----
#define DPP_ADD(v, ctrl)                                                     \
    v += __int_as_float(__builtin_amdgcn_update_dpp(                         \
        0, __float_as_int(v), (ctrl), 0xF, 0xF, true))

__device__ __forceinline__ float rl(float x, int lane) {
    return __int_as_float(__builtin_amdgcn_readlane(__float_as_int(x), lane));
}

__global__ __launch_bounds__(NTHREADS, 4) void em_pass(
    const float* __restrict__ mu_phi,
    const float* __restrict__ log_cov_phi,
    const float* __restrict__ pi_k,
    const float* __restrict__ mu_k,
    const float* __restrict__ log_cov_k,
    float* __restrict__ gamma_out,
    float* __restrict__ out_tail,   // pi_new | mu_new | log_cov_new
    float* __restrict__ ws)
{
    const int lane = threadIdx.x & 63;                 // = cluster index
    const int wave = threadIdx.x >> 6;
    const int gw = __builtin_amdgcn_readfirstlane(blockIdx.x * WPB + wave); // tile id

    // ---- per-lane cluster constants (icov folded into mk2) ----
    const float lck  = log_cov_k[lane];
    const float icov = __expf(-lck);
    const float pik  = pi_k[lane];

    float mk2[P];
    float n2k = 0.f;
#pragma unroll
    for (int d = 0; d < P; ++d) {
        const float m = mu_k[lane * P + d];
        mk2[d] = icov * m;
        n2k = fmaf(m, m, n2k);
    }
    // exponent = sum_d row[d]*mk2[d] - 0.5*icov*u + 16*lcp - Ak
    const float Ak     = 0.5f * (32.f * lck - 32.f + icov * n2k) - __logf(pik);
    const float negAk  = -Ak;
    const float nhicov = -0.5f * icov;

    float accN = 0.f, accS = 0.f;
    float accM[P];
#pragma unroll
    for (int d = 0; d < P; ++d) accM[d] = 0.f;

    const int start = gw * TILE;
    const int cnt   = (NPTS - start < TILE) ? (NPTS - start) : TILE;

    // ---- u-phase: lane = point. Coalesced float4 loads, u & lcp only ----
    float u_v = 0.f, bl_v = 0.f;
    if (lane < cnt) {
        const float4* r4 =
            reinterpret_cast<const float4*>(mu_phi + (size_t)(start + lane) * P);
        float n2 = 0.f;
#pragma unroll 1
        for (int q = 0; q < 8; q += 4) {
            float4 a = r4[q], b = r4[q + 1], c = r4[q + 2], e = r4[q + 3];
            n2 = fmaf(a.x, a.x, n2); n2 = fmaf(a.y, a.y, n2);
            n2 = fmaf(a.z, a.z, n2); n2 = fmaf(a.w, a.w, n2);
            n2 = fmaf(b.x, b.x, n2); n2 = fmaf(b.y, b.y, n2);
            n2 = fmaf(b.z, b.z, n2); n2 = fmaf(b.w, b.w, n2);
            n2 = fmaf(c.x, c.x, n2); n2 = fmaf(c.y, c.y, n2);
            n2 = fmaf(c.z, c.z, n2); n2 = fmaf(c.w, c.w, n2);
            n2 = fmaf(e.x, e.x, n2); n2 = fmaf(e.y, e.y, n2);
            n2 = fmaf(e.z, e.z, n2); n2 = fmaf(e.w, e.w, n2);
        }
        const float lcp = log_cov_phi[start + lane];
        u_v  = fmaf(32.f, __expf(lcp), n2);   // P*e^lcp + ||phi||^2
        bl_v = 16.f * lcp;
    }

    // ---- per-point phase: lane = cluster; rows broadcast through the SCALAR
    //      pipe (s_load -> SGPRs, reused by all 64 lanes), software
    //      double-buffered so each lgkmcnt drain is covered by one full
    //      iteration (~340 cy) of compute. NO LDS, NO vector loads here. ----
    {
        const float4* rq =
            reinterpret_cast<const float4*>(mu_phi + (size_t)start * P);
        // current row buffer (SGPR quads)
        float4 c0 = rq[0], c1 = rq[1], c2 = rq[2], c3 = rq[3];
        float4 c4 = rq[4], c5 = rq[5], c6 = rq[6], c7 = rq[7];

#pragma unroll 2
        for (int p = 0; p < cnt; ++p) {
            // ---- prefetch next row into the alternate buffer (uniform addr) ----
            const int pn = (p + 1 < cnt) ? (p + 1) : p;
            const float4* nq =
                reinterpret_cast<const float4*>(mu_phi + (size_t)(start + pn) * P);
            float4 n0 = nq[0], n1 = nq[1], n2q = nq[2], n3 = nq[3];
            float4 n4 = nq[4], n5 = nq[5], n6 = nq[6], n7 = nq[7];

            const int i = start + p;
            const float u_s  = rl(u_v, p);
            const float bl_s = rl(bl_v, p);

            // 4 independent FMA chains (8 deep each); row operand is SGPR
            float d0 = 0.f, d1 = 0.f, d2 = 0.f, d3 = 0.f;
#define DOT4(q, base)                                                        \
            d0 = fmaf(q.x, mk2[base + 0], d0);                               \
            d1 = fmaf(q.y, mk2[base + 1], d1);                               \
            d2 = fmaf(q.z, mk2[base + 2], d2);                               \
            d3 = fmaf(q.w, mk2[base + 3], d3)
            DOT4(c0, 0);  DOT4(c1, 4);  DOT4(c2, 8);  DOT4(c3, 12);
            DOT4(c4, 16); DOT4(c5, 20); DOT4(c6, 24); DOT4(c7, 28);
#undef DOT4
            const float dot = (d0 + d1) + (d2 + d3);

            // arg = dot + (nhicov*u - Ak) + 16*lcp
            const float tpart = fmaf(nhicov, u_s, negAk);
            const float w = __expf((dot + tpart) + bl_s);

            // wave-64 sum via DPP (VALU) + readlane combine
            float v = w;
            DPP_ADD(v, 0xB1);   // quad_perm xor1
            DPP_ADD(v, 0x4E);   // quad_perm xor2
            DPP_ADD(v, 0x128);  // row_ror:8
            DPP_ADD(v, 0x124);  // row_ror:4  -> each lane = its 16-row sum
            const float sum = (rl(v, 0) + rl(v, 16)) + (rl(v, 32) + rl(v, 48));

            const float g = fmaf(w, __builtin_amdgcn_rcpf(sum), DETC);
            __builtin_nontemporal_store(g, gamma_out + (size_t)i * K + lane);

            accN += g;
            accS  = fmaf(g, u_s, accS);
#define ACC4(q, base)                                                        \
            accM[base + 0] = fmaf(g, q.x, accM[base + 0]);                   \
            accM[base + 1] = fmaf(g, q.y, accM[base + 1]);                   \
            accM[base + 2] = fmaf(g, q.z, accM[base + 2]);                   \
            accM[base + 3] = fmaf(g, q.w, accM[base + 3])
            ACC4(c0, 0);  ACC4(c1, 4);  ACC4(c2, 8);  ACC4(c3, 12);
            ACC4(c4, 16); ACC4(c5, 20); ACC4(c6, 24); ACC4(c7, 28);
#undef ACC4

            // rotate buffers (renamed away under unroll 2)
            c0 = n0; c1 = n1; c2 = n2q; c3 = n3;
            c4 = n4; c5 = n5; c6 = n6;  c7 = n7;
        }
    }

    // ---- block combine in LDS, then one set of striped global atomics ----
    __shared__ float red[WS_FLOATS];   // [0,K) N | [K,2K) S | [2K,..) M[d][k]
    for (int idx = threadIdx.x; idx < WS_FLOATS; idx += NTHREADS) red[idx] = 0.f;
    __syncthreads();

    atomicAdd(&red[lane], accN);
    atomicAdd(&red[K + lane], accS);
#pragma unroll
    for (int d = 0; d < P; ++d) atomicAdd(&red[2 * K + d * K + lane], accM[d]);
    __syncthreads();

    // striped cross-block combine: contention per address = NBLOCKS/NCOPIES
    float* wsc = ws + (size_t)(blockIdx.x & (NCOPIES - 1)) * WS_FLOATS;
    for (int idx = threadIdx.x; idx < WS_FLOATS; idx += NTHREADS)
        atomicAdd(&wsc[idx], red[idx]);
    __syncthreads();   // all this block's global atomics drained

    // ---- decoupled finalize: last block reduces the copies + small outputs ----
    __shared__ int lastf;
    if (threadIdx.x == 0) {
        __threadfence();
        const int c = atomicAdd((int*)(ws + (size_t)NCOPIES * WS_FLOATS), 1);
        lastf = (c == NBLOCKS - 1);
    }
    __syncthreads();
    if (lastf) {
        __threadfence();
        for (int idx = threadIdx.x; idx < WS_FLOATS; idx += NTHREADS) {
            float s = 0.f;
#pragma unroll 4
            for (int c = 0; c < NCOPIES; ++c)
                s += __hip_atomic_load(&ws[(size_t)c * WS_FLOATS + idx],
                                       __ATOMIC_RELAXED, __HIP_MEMORY_SCOPE_AGENT);
            red[idx] = s;
        }
        __syncthreads();

        const int k = threadIdx.x;
        if (k < K) {
            const float Nk = red[k];
            const float S  = red[K + k];
            float* pi_new      = out_tail;
            float* mu_new      = out_tail + K;
            float* log_cov_new = out_tail + K + K * P;

            pi_new[k] = Nk / (float)NPTS;
            const float invN = 1.f / Nk;
            float m2 = 0.f;
#pragma unroll
            for (int d = 0; d < P; ++d) {
                const float md = red[2 * K + d * K + k] * invN;
                mu_new[k * P + d] = md;
                m2 = fmaf(md, md, m2);
            }
            const float cov = (S - Nk * m2) / (32.f * Nk);
            log_cov_new[k] = logf(cov);
        }
    }
}

extern "C" void kernel_launch(void* const* d_in, const int* in_sizes, int n_in,
                              void* d_out, int out_size, void* d_ws, size_t ws_size,
                              hipStream_t stream)
{
    const float* mu_phi      = (const float*)d_in[0];
    const float* log_cov_phi = (const float*)d_in[1];
    const float* pi_k        = (const float*)d_in[2];
    const float* mu_k        = (const float*)d_in[3];
    const float* log_cov_k   = (const float*)d_in[4];
    float* out = (float*)d_out;
    float* ws  = (float*)d_ws;

    hipMemsetAsync(ws, 0, ((size_t)NCOPIES * WS_FLOATS + 1) * sizeof(float), stream);
    em_pass<<<NBLOCKS, NTHREADS, 0, stream>>>(mu_phi, log_cov_phi, pi_k, mu_k,
                                              log_cov_k, out,
                                              out + (size_t)NPTS * K, ws);
}